// Round 4
// baseline (2998.253 us; speedup 1.0000x reference)
//
#include <hip/hip_runtime.h>
#include <cfloat>
#include <climits>

#define T_TOKENS 65536
#define K_EMB 4096
#define D_DIM 256
#define QOFF ((size_t)T_TOKENS * D_DIM)   // 16777216
#define BT 128
#define BK 128
#define BD 32

// fp32 multiply with contraction into a later add BLOCKED (numpy squares into a
// temp array: the square is rounded before the sum touches it).
__device__ __forceinline__ float fmul_nc(float a, float b) {
    float c = a * b;
    asm volatile("" : "+v"(c));
    return c;
}

__device__ __forceinline__ double wave_sum_d(double v) {
#pragma unroll
    for (int o = 32; o >= 1; o >>= 1) v += __shfl_down(v, o, 64);
    return v;
}

// Kernel A: A32[t] = np.sum(z[t]**2) emulating numpy's fp32 pairwise_sum for
// n=256: two halves of 128, each with 8 strided accumulators r[j] summed in
// ascending block order, combined ((r0+r1)+(r2+r3))+((r4+r5)+(r6+r7)), then
// half0 + half1. All fp32, squares rounded individually.
__global__ __launch_bounds__(256)
void a32_kernel(const float* __restrict__ z, float* __restrict__ a32) {
    __shared__ float lds[64][257];   // +1 pad: conflict-free row-per-thread reads
    const int tid = threadIdx.x;
    const int t0 = blockIdx.x * 256;
    for (int sub = 0; sub < 4; sub++) {
        const int tb = t0 + sub * 64;
        __syncthreads();
        for (int idx = tid; idx < 64 * 256; idx += 256) {
            const int r = idx >> 8, c = idx & 255;
            lds[r][c] = z[(size_t)(tb + r) * D_DIM + c];
        }
        __syncthreads();
        if (tid < 64) {
            const float* row = lds[tid];
            float S[2];
            for (int h = 0; h < 2; h++) {
                const float* p = row + h * 128;
                float r[8];
#pragma unroll
                for (int j = 0; j < 8; j++) r[j] = fmul_nc(p[j], p[j]);
                for (int m = 1; m < 16; m++) {   // sequential m: numpy block order
#pragma unroll
                    for (int j = 0; j < 8; j++) r[j] += fmul_nc(p[8 * m + j], p[8 * m + j]);
                }
                S[h] = ((r[0] + r[1]) + (r[2] + r[3])) + ((r[4] + r[5]) + (r[6] + r[7]));
            }
            a32[tb + tid] = S[0] + S[1];
        }
    }
}

// Kernel B: C32[k] = fp32(||e_k||^2). Its exact rounding is irrelevant: the
// reference's final +C add is annihilated by fp32 rounding (C < ulp/2 at 256),
// but we keep the add for faithfulness.
__global__ void c32_kernel(const float* __restrict__ emb, float* __restrict__ c32) {
    const int k = blockIdx.x;
    const double v = (double)emb[(size_t)k * D_DIM + threadIdx.x];
    double s = wave_sum_d(v * v);
    __shared__ double wsm[4];
    const int lane = threadIdx.x & 63, w = threadIdx.x >> 6;
    if (lane == 0) wsm[w] = s;
    __syncthreads();
    if (threadIdx.x == 0) c32[k] = (float)(wsm[0] + wsm[1] + wsm[2] + wsm[3]);
}

struct Tiles { float zt[BD][BT]; float et[BD][BK]; };
struct Merge { float rb[16][BT]; int ri[16][BT]; };

// Kernel C: fp32 GEMM with strictly d-ordered sequential FMA chains per (t,k)
// (emulating BLAS sgemm accumulation), then V = fl32(fl32(A32 - 2*acc) + C32),
// argmin over k with numpy first-index tiebreak.
__global__ __launch_bounds__(256, 2)
void argmin_np_kernel(const float* __restrict__ z, const float* __restrict__ emb,
                      const float* __restrict__ a32, const float* __restrict__ c32,
                      int* __restrict__ selw)
{
    __shared__ union { Tiles t; Merge m; } sm;
    const int tid = threadIdx.x;
    const int tx = tid & 15;   // code group (8 codes)
    const int ty = tid >> 4;   // token group (8 tokens)
    const int t0 = blockIdx.x * BT;
    const int dg = tid & 7;
    const int tt = tid >> 3;

    float a32r[8];
#pragma unroll
    for (int i = 0; i < 8; i++) a32r[i] = a32[t0 + ty * 8 + i];

    float bv[8];
    int bi[8];
#pragma unroll
    for (int i = 0; i < 8; i++) { bv[i] = FLT_MAX; bi[i] = INT_MAX; }

    for (int kt = 0; kt < K_EMB; kt += BK) {
        float acc[8][8];
#pragma unroll
        for (int i = 0; i < 8; i++)
#pragma unroll
            for (int j = 0; j < 8; j++) acc[i][j] = 0.0f;

        for (int dc = 0; dc < D_DIM; dc += BD) {
            __syncthreads();
#pragma unroll
            for (int r = 0; r < 4; r++) {
                const int t = tt + r * 32;
                float4 v = *(const float4*)(z + (size_t)(t0 + t) * D_DIM + dc + dg * 4);
                sm.t.zt[dg * 4 + 0][t] = v.x; sm.t.zt[dg * 4 + 1][t] = v.y;
                sm.t.zt[dg * 4 + 2][t] = v.z; sm.t.zt[dg * 4 + 3][t] = v.w;
                float4 w = *(const float4*)(emb + (size_t)(kt + t) * D_DIM + dc + dg * 4);
                sm.t.et[dg * 4 + 0][t] = w.x; sm.t.et[dg * 4 + 1][t] = w.y;
                sm.t.et[dg * 4 + 2][t] = w.z; sm.t.et[dg * 4 + 3][t] = w.w;
            }
            __syncthreads();
            // d ascends strictly dc+0 .. dc+BD-1: each acc[i][j] is ONE ordered
            // sequential fp32 FMA chain over d = 0..255 (no partial accumulators).
#pragma unroll 2
            for (int dd = 0; dd < BD; dd++) {
                float a[8], b[8];
                *(float4*)&a[0] = *(const float4*)&sm.t.zt[dd][ty * 8];
                *(float4*)&a[4] = *(const float4*)&sm.t.zt[dd][ty * 8 + 4];
                *(float4*)&b[0] = *(const float4*)&sm.t.et[dd][tx * 8];
                *(float4*)&b[4] = *(const float4*)&sm.t.et[dd][tx * 8 + 4];
#pragma unroll
                for (int i = 0; i < 8; i++)
#pragma unroll
                    for (int j = 0; j < 8; j++)
                        acc[i][j] = fmaf(a[i], b[j], acc[i][j]);
            }
        }
        // numpy: V = fl32( fl32(A32 - fl32(2*M)) + C32 ); 2*M is exact (pow2).
#pragma unroll
        for (int j = 0; j < 8; j++) {
            const int k = kt + tx * 8 + j;
            const float ck = c32[k];
#pragma unroll
            for (int i = 0; i < 8; i++) {
                const float v1 = a32r[i] - 2.0f * acc[i][j];
                const float v2 = v1 + ck;
                // per-thread k strictly ascending -> strict < keeps first index
                if (v2 < bv[i]) { bv[i] = v2; bi[i] = k; }
            }
        }
    }

    __syncthreads();
#pragma unroll
    for (int i = 0; i < 8; i++) {
        sm.m.rb[tx][ty * 8 + i] = bv[i];
        sm.m.ri[tx][ty * 8 + i] = bi[i];
    }
    __syncthreads();
    if (tid < BT) {
        float B = sm.m.rb[0][tid];
        int I = sm.m.ri[0][tid];
        for (int e = 1; e < 16; e++) {
            const float cv = sm.m.rb[e][tid];
            const int ci = sm.m.ri[e][tid];
            if (cv < B || (cv == B && ci < I)) { B = cv; I = ci; }
        }
        selw[t0 + tid] = I;
    }
}

// Kernel D: gather quantized rows, write indices, fp64 loss partials.
__global__ __launch_bounds__(256)
void gather_kernel(const float* __restrict__ z, const float* __restrict__ emb,
                   const int* __restrict__ selw, float* __restrict__ out,
                   double* __restrict__ partials)
{
    const int tid = threadIdx.x;
    const int base = blockIdx.x * 64;
    __shared__ double lsm[4];
    double lacc = 0.0;
    for (int ti = 0; ti < 64; ti++) {
        const int t = base + ti;
        const int sel = selw[t];
        const float ev = emb[(size_t)sel * D_DIM + tid];
        const float zv = z[(size_t)t * D_DIM + tid];
        out[(size_t)t * D_DIM + tid] = ev;
        if (tid == 0) out[QOFF + t] = (float)sel;
        const double df = (double)zv - (double)ev;
        lacc += df * df;
    }
    lacc = wave_sum_d(lacc);
    const int lane = tid & 63, w = tid >> 6;
    if (lane == 0) lsm[w] = lacc;
    __syncthreads();
    if (tid == 0) partials[blockIdx.x] = lsm[0] + lsm[1] + lsm[2] + lsm[3];
}

__global__ void finalize_kernel(const double* __restrict__ partials, float* __restrict__ out) {
    __shared__ double rsm[4];
    const int tid = threadIdx.x;
    double s = 0.0;
    for (int i = tid; i < 1024; i += 256) s += partials[i];
    s = wave_sum_d(s);
    if ((tid & 63) == 0) rsm[tid >> 6] = s;
    __syncthreads();
    if (tid == 0) {
        const double mean = (rsm[0] + rsm[1] + rsm[2] + rsm[3]) / (double)QOFF;
        out[QOFF + T_TOKENS] = (float)(1.25 * mean);
    }
}

extern "C" void kernel_launch(void* const* d_in, const int* in_sizes, int n_in,
                              void* d_out, int out_size, void* d_ws, size_t ws_size,
                              hipStream_t stream)
{
    const float* z = (const float*)d_in[0];
    const float* emb = (const float*)d_in[1];
    float* out = (float*)d_out;
    char* ws = (char*)d_ws;

    float* a32 = (float*)ws;                         // 65536*4 = 262144
    float* c32 = (float*)(ws + 262144);              // 4096*4  = 16384
    int* selw = (int*)(ws + 278528);                 // 65536*4 = 262144
    double* partials = (double*)(ws + 540672);       // 1024*8  = 8192

    a32_kernel<<<T_TOKENS / 256, 256, 0, stream>>>(z, a32);
    c32_kernel<<<K_EMB, 256, 0, stream>>>(emb, c32);
    argmin_np_kernel<<<T_TOKENS / BT, 256, 0, stream>>>(z, emb, a32, c32, selw);
    gather_kernel<<<T_TOKENS / 64, 256, 0, stream>>>(z, emb, selw, out, partials);
    finalize_kernel<<<1, 256, 0, stream>>>(partials, out);
}

// Round 5
// 2860.741 us; speedup vs baseline: 1.0481x; 1.0481x over previous
//
#include <hip/hip_runtime.h>
#include <cfloat>
#include <climits>

#define T_TOKENS 65536
#define K_EMB 4096
#define D_DIM 256
#define QOFF ((size_t)T_TOKENS * D_DIM)   // 16777216
#define BT 128        // tokens per block
#define KHALF 2048    // codes per k-split half
#define NTILE 16      // k-tiles per half (128 codes each)
#define ZSTR 36       // LDS row stride in floats (144 B, 16B-aligned, conflict-free)

// fp32 multiply, contraction into later add blocked (numpy rounds the square first)
__device__ __forceinline__ float fmul_nc(float a, float b) {
    float c = a * b;
    asm volatile("" : "+v"(c));
    return c;
}

__device__ __forceinline__ double wave_sum_d(double v) {
#pragma unroll
    for (int o = 32; o >= 1; o >>= 1) v += __shfl_down(v, o, 64);
    return v;
}

// A32[t] = np.float32 pairwise sum of z[t]**2 (two 128-halves, 8 strided
// accumulators, ((r0+r1)+(r2+r3))+((r4+r5)+(r6+r7)), then h0+h1). Validated r4.
__global__ __launch_bounds__(256)
void a32_kernel(const float* __restrict__ z, float* __restrict__ a32) {
    __shared__ float lds[64][257];
    const int tid = threadIdx.x;
    const int t0 = blockIdx.x * 256;
    for (int sub = 0; sub < 4; sub++) {
        const int tb = t0 + sub * 64;
        __syncthreads();
        for (int idx = tid; idx < 64 * 256; idx += 256) {
            const int r = idx >> 8, c = idx & 255;
            lds[r][c] = z[(size_t)(tb + r) * D_DIM + c];
        }
        __syncthreads();
        if (tid < 64) {
            const float* row = lds[tid];
            float S[2];
            for (int h = 0; h < 2; h++) {
                const float* p = row + h * 128;
                float r[8];
#pragma unroll
                for (int j = 0; j < 8; j++) r[j] = fmul_nc(p[j], p[j]);
                for (int m = 1; m < 16; m++) {
#pragma unroll
                    for (int j = 0; j < 8; j++) r[j] += fmul_nc(p[8 * m + j], p[8 * m + j]);
                }
                S[h] = ((r[0] + r[1]) + (r[2] + r[3])) + ((r[4] + r[5]) + (r[6] + r[7]));
            }
            a32[tb + tid] = S[0] + S[1];
        }
    }
}

// C32[k] = fp32(||e_k||^2) — the +C add is annihilated by fp32 rounding anyway.
__global__ void c32_kernel(const float* __restrict__ emb, float* __restrict__ c32) {
    const int k = blockIdx.x;
    const double v = (double)emb[(size_t)k * D_DIM + threadIdx.x];
    double s = wave_sum_d(v * v);
    __shared__ double wsm[4];
    const int lane = threadIdx.x & 63, w = threadIdx.x >> 6;
    if (lane == 0) wsm[w] = s;
    __syncthreads();
    if (threadIdx.x == 0) c32[k] = (float)(wsm[0] + wsm[1] + wsm[2] + wsm[3]);
}

// Conflict-free argmin GEMM. Row-major LDS tiles [row][ZSTR]; fragment reads are
// float4 along d; per-(t,k) fp32 fmaf chain in strictly ascending d order
// (bit-identical to the validated round-4 chain). K-split across blockIdx.y.
__global__ __launch_bounds__(256, 2)
void argmin_np_kernel(const float* __restrict__ z, const float* __restrict__ emb,
                      const float* __restrict__ a32, const float* __restrict__ c32,
                      float* __restrict__ bvo, int* __restrict__ bio)
{
    __shared__ union {
        struct { float zt[BT * ZSTR]; float et[BT * ZSTR]; } t;   // 36864 B
        struct { float rb[16][BT]; int ri[16][BT]; } m;
    } sm;

    const int tid = threadIdx.x;
    const int tx = tid & 15;        // code group: codes 16j+tx
    const int ty = tid >> 4;        // token group: tokens 16i+ty
    const int t0 = blockIdx.x * BT;
    const int k0 = blockIdx.y * KHALF;
    const int sr = tid >> 3;        // staging row base (0..31)
    const int dg = tid & 7;         // staging float4 column

    float a32r[8];
#pragma unroll
    for (int i = 0; i < 8; i++) a32r[i] = a32[t0 + 16 * i + ty];

    float bv[8];
    int bi[8];
#pragma unroll
    for (int i = 0; i < 8; i++) { bv[i] = FLT_MAX; bi[i] = INT_MAX; }

    float acc[8][8];
#pragma unroll
    for (int i = 0; i < 8; i++)
#pragma unroll
        for (int j = 0; j < 8; j++) acc[i][j] = 0.0f;

    float4 gz[4], ge[4];
    // prefetch chunk 0 (k-tile 0, d-chunk 0)
#pragma unroll
    for (int s = 0; s < 4; s++) {
        gz[s] = *(const float4*)(z + (size_t)(t0 + sr + 32 * s) * D_DIM + dg * 4);
        ge[s] = *(const float4*)(emb + (size_t)(k0 + sr + 32 * s) * D_DIM + dg * 4);
    }

    for (int ci = 0; ci < NTILE * 8; ci++) {
        __syncthreads();   // previous chunk's readers done
#pragma unroll
        for (int s = 0; s < 4; s++) {
            *(float4*)&sm.t.zt[(sr + 32 * s) * ZSTR + dg * 4] = gz[s];
            *(float4*)&sm.t.et[(sr + 32 * s) * ZSTR + dg * 4] = ge[s];
        }
        __syncthreads();
        if (ci < NTILE * 8 - 1) {   // prefetch next chunk; vmcnt waits at next store
            const int cn = ci + 1;
            const int dc = (cn & 7) * 32;
            const int kb = k0 + (cn >> 3) * BT;
#pragma unroll
            for (int s = 0; s < 4; s++) {
                gz[s] = *(const float4*)(z + (size_t)(t0 + sr + 32 * s) * D_DIM + dc + dg * 4);
                ge[s] = *(const float4*)(emb + (size_t)(kb + sr + 32 * s) * D_DIM + dc + dg * 4);
            }
        }
        // compute this chunk: d ascends (q*4 + {x,y,z,w}) within chunk; chunks
        // ascend in d within a k-tile -> exact sequential 0..255 chain per acc.
#pragma unroll
        for (int q = 0; q < 8; q++) {
            float4 av[8], bw[8];
#pragma unroll
            for (int i = 0; i < 8; i++)
                av[i] = *(const float4*)&sm.t.zt[(16 * i + ty) * ZSTR + q * 4];
#pragma unroll
            for (int j = 0; j < 8; j++)
                bw[j] = *(const float4*)&sm.t.et[(16 * j + tx) * ZSTR + q * 4];
#pragma unroll
            for (int i = 0; i < 8; i++)
#pragma unroll
                for (int j = 0; j < 8; j++) {
                    acc[i][j] = fmaf(av[i].x, bw[j].x, acc[i][j]);
                    acc[i][j] = fmaf(av[i].y, bw[j].y, acc[i][j]);
                    acc[i][j] = fmaf(av[i].z, bw[j].z, acc[i][j]);
                    acc[i][j] = fmaf(av[i].w, bw[j].w, acc[i][j]);
                }
        }
        if ((ci & 7) == 7) {   // k-tile epilogue: V = fl32(fl32(A-2M)+C), argmin
            const int kb = k0 + (ci >> 3) * BT;
#pragma unroll
            for (int j = 0; j < 8; j++) {
                const int k = kb + 16 * j + tx;   // per-thread k strictly ascending
                const float ck = c32[k];
#pragma unroll
                for (int i = 0; i < 8; i++) {
                    const float v1 = a32r[i] - 2.0f * acc[i][j];
                    const float v2 = v1 + ck;
                    if (v2 < bv[i]) { bv[i] = v2; bi[i] = k; }
                    acc[i][j] = 0.0f;
                }
            }
        }
    }

    __syncthreads();   // tiles dead; reuse LDS for merge
#pragma unroll
    for (int i = 0; i < 8; i++) {
        sm.m.rb[tx][16 * i + ty] = bv[i];
        sm.m.ri[tx][16 * i + ty] = bi[i];
    }
    __syncthreads();
    if (tid < BT) {
        float B = sm.m.rb[0][tid];
        int I = sm.m.ri[0][tid];
#pragma unroll
        for (int e = 1; e < 16; e++) {
            const float cv = sm.m.rb[e][tid];
            const int ci2 = sm.m.ri[e][tid];
            if (cv < B || (cv == B && ci2 < I)) { B = cv; I = ci2; }
        }
        bvo[(size_t)blockIdx.y * T_TOKENS + t0 + tid] = B;
        bio[(size_t)blockIdx.y * T_TOKENS + t0 + tid] = I;
    }
}

// Merge k-split halves, gather quantized rows, write indices, fp64 loss partials.
__global__ __launch_bounds__(256)
void gather_kernel(const float* __restrict__ z, const float* __restrict__ emb,
                   const float* __restrict__ bvh, const int* __restrict__ bih,
                   float* __restrict__ out, double* __restrict__ partials)
{
    const int tid = threadIdx.x;
    const int base = blockIdx.x * 64;
    __shared__ double lsm[4];
    double lacc = 0.0;
    for (int ti = 0; ti < 64; ti++) {
        const int t = base + ti;
        // numpy first-index: tie -> half 0 (its ks are all smaller)
        const int sel = (bvh[T_TOKENS + t] < bvh[t]) ? bih[T_TOKENS + t] : bih[t];
        const float ev = emb[(size_t)sel * D_DIM + tid];
        const float zv = z[(size_t)t * D_DIM + tid];
        out[(size_t)t * D_DIM + tid] = ev;
        if (tid == 0) out[QOFF + t] = (float)sel;
        const double df = (double)zv - (double)ev;
        lacc += df * df;
    }
    lacc = wave_sum_d(lacc);
    const int lane = tid & 63, w = tid >> 6;
    if (lane == 0) lsm[w] = lacc;
    __syncthreads();
    if (tid == 0) partials[blockIdx.x] = lsm[0] + lsm[1] + lsm[2] + lsm[3];
}

__global__ void finalize_kernel(const double* __restrict__ partials, float* __restrict__ out) {
    __shared__ double rsm[4];
    const int tid = threadIdx.x;
    double s = 0.0;
    for (int i = tid; i < 1024; i += 256) s += partials[i];
    s = wave_sum_d(s);
    if ((tid & 63) == 0) rsm[tid >> 6] = s;
    __syncthreads();
    if (tid == 0) {
        const double mean = (rsm[0] + rsm[1] + rsm[2] + rsm[3]) / (double)QOFF;
        out[QOFF + T_TOKENS] = (float)(1.25 * mean);
    }
}

extern "C" void kernel_launch(void* const* d_in, const int* in_sizes, int n_in,
                              void* d_out, int out_size, void* d_ws, size_t ws_size,
                              hipStream_t stream)
{
    const float* z = (const float*)d_in[0];
    const float* emb = (const float*)d_in[1];
    float* out = (float*)d_out;
    char* ws = (char*)d_ws;

    float* a32 = (float*)ws;                          // 262144 B
    float* c32 = (float*)(ws + 262144);               // 16384 B
    float* bvh = (float*)(ws + 278528);               // 2*65536*4 = 524288 B
    int* bih = (int*)(ws + 802816);                   // 524288 B
    double* partials = (double*)(ws + 1327104);       // 8192 B

    a32_kernel<<<T_TOKENS / 256, 256, 0, stream>>>(z, a32);
    c32_kernel<<<K_EMB, 256, 0, stream>>>(emb, c32);
    argmin_np_kernel<<<dim3(T_TOKENS / BT, 2), 256, 0, stream>>>(z, emb, a32, c32, bvh, bih);
    gather_kernel<<<T_TOKENS / 64, 256, 0, stream>>>(z, emb, bvh, bih, out, partials);
    finalize_kernel<<<1, 256, 0, stream>>>(partials, out);
}